// Round 2
// baseline (7647.548 us; speedup 1.0000x reference)
//
#include <hip/hip_runtime.h>
#include <hip/hip_bf16.h>
#include <math.h>

typedef unsigned short u16;
typedef unsigned int   u32;

// ---------------- bf16 helpers ----------------
__device__ __forceinline__ float b2f(u16 u) {
    union { u32 i; float f; } v; v.i = ((u32)u) << 16; return v.f;
}
__device__ __forceinline__ u16 f2b(float f) {
    union { float f; u32 i; } v; v.f = f;
    u32 x = v.i;
    u32 r = x + 0x7fffu + ((x >> 16) & 1u);   // RNE
    return (u16)(r >> 16);
}
__device__ __forceinline__ void up2(u32 u, float& lo, float& hi) {
    union { u32 i; float f; } a, b;
    a.i = u << 16; b.i = u & 0xffff0000u;
    lo = a.f; hi = b.f;
}
__device__ __forceinline__ void up8(uint4 w, float* f) {
    up2(w.x, f[0], f[1]); up2(w.y, f[2], f[3]);
    up2(w.z, f[4], f[5]); up2(w.w, f[6], f[7]);
}
__device__ __forceinline__ u32 pk2(float a, float b) {
    return (u32)f2b(a) | ((u32)f2b(b) << 16);
}

#define SCALE_ 0.17677669529663687f   // 32^-0.5
#define EPS_   1e-3f

// =====================================================================
// Kernel A: shifted-window attention + proj + LN1 + residual -> x1 (fp32)
// one block per window: win = b*256 + wr*16 + wc.  x1 is written into d_out.
// =====================================================================
__global__ __launch_bounds__(256) void swin_attn(
    const float* __restrict__ x, const float* __restrict__ w_qkv, const float* __restrict__ b_qkv,
    const float* __restrict__ bias_table, const float* __restrict__ w_proj, const float* __restrict__ b_proj,
    const float* __restrict__ g1, const float* __restrict__ be1,
    const int* __restrict__ rel_index, const float* __restrict__ attn_mask,
    float* __restrict__ x1out)
{
    __shared__ __align__(16) u16 smem[4 * 64 * 128];   // 64 KB
    u16* sm_xw = smem;            // 16 KB: window input (bf16); later attn-out (bf16)
    u16* sm_q  = smem + 8192;     // 16 KB: [h][t][d] bf16 (q pre-scaled)
    u16* sm_k  = smem + 16384;    // 16 KB
    u16* sm_v  = smem + 24576;    // 16 KB
    float* sm_o2 = reinterpret_cast<float*>(smem + 8192);  // 32 KB fp32, aliases q+k after attention

    const int tid = threadIdx.x;
    const int win = blockIdx.x;
    const int b  = win >> 8;
    const int wr = (win >> 4) & 15;
    const int wc = win & 15;

    // ---- Phase 1: load shifted window (fp32 -> bf16 LDS) ----
    for (int e = tid * 8; e < 8192; e += 2048) {
        const int t = e >> 7, c = e & 127;
        const int i = t >> 3, j = t & 7;
        const int hh = (wr * 8 + i + 4) & 127;
        const int ww = (wc * 8 + j + 4) & 127;
        const size_t gbase = ((size_t)((b * 128 + hh) * 128 + ww)) * 128;
        const float4 a0 = *reinterpret_cast<const float4*>(x + gbase + c);
        const float4 a1 = *reinterpret_cast<const float4*>(x + gbase + c + 4);
        uint4 st;
        st.x = pk2(a0.x, a0.y); st.y = pk2(a0.z, a0.w);
        st.z = pk2(a1.x, a1.y); st.w = pk2(a1.z, a1.w);
        *reinterpret_cast<uint4*>(sm_xw + e) = st;
    }
    __syncthreads();

    // ---- Phase 2: qkv = xw @ w_qkv + b_qkv  (each thread: 8 adjacent outputs) ----
    for (int rep = 0; rep < 12; rep++) {
        const int ol = (rep * 256 + tid) * 8;     // 0..24568
        const int t = ol / 384;
        const int o = ol - t * 384;
        float acc[8];
        {
            const float4 b0 = *reinterpret_cast<const float4*>(b_qkv + o);
            const float4 b1 = *reinterpret_cast<const float4*>(b_qkv + o + 4);
            acc[0] = b0.x; acc[1] = b0.y; acc[2] = b0.z; acc[3] = b0.w;
            acc[4] = b1.x; acc[5] = b1.y; acc[6] = b1.z; acc[7] = b1.w;
        }
        const u16* xr = sm_xw + t * 128;
        const float* wp = w_qkv + o;
        #pragma unroll 2
        for (int c = 0; c < 128; c++) {
            const float xv = b2f(xr[c]);
            const float4 w0 = *reinterpret_cast<const float4*>(wp + c * 384);
            const float4 w1 = *reinterpret_cast<const float4*>(wp + c * 384 + 4);
            acc[0] += xv * w0.x; acc[1] += xv * w0.y; acc[2] += xv * w0.z; acc[3] += xv * w0.w;
            acc[4] += xv * w1.x; acc[5] += xv * w1.y; acc[6] += xv * w1.z; acc[7] += xv * w1.w;
        }
        const int s = o >> 7;
        const int hh = (o >> 5) & 3;
        const int d = o & 31;
        u16* dst = (s == 0) ? sm_q : (s == 1) ? sm_k : sm_v;
        const float sc = (s == 0) ? SCALE_ : 1.0f;
        uint4 st;
        st.x = pk2(acc[0] * sc, acc[1] * sc);
        st.y = pk2(acc[2] * sc, acc[3] * sc);
        st.z = pk2(acc[4] * sc, acc[5] * sc);
        st.w = pk2(acc[6] * sc, acc[7] * sc);
        *reinterpret_cast<uint4*>(dst + (hh * 64 + t) * 32 + d) = st;
    }
    __syncthreads();

    // ---- Phase 3: scores + bias + mask + softmax + AV ; one (head,row) per thread ----
    {
        const int h = tid >> 6;
        const int i = tid & 63;
        float qr[32];
        {
            const uint4* qrow = reinterpret_cast<const uint4*>(sm_q + (h * 64 + i) * 32);
            #pragma unroll
            for (int g = 0; g < 4; g++) { uint4 qq = qrow[g]; up8(qq, qr + g * 8); }
        }
        float p[64];
        float mx = -3.0e38f;
        const int mbase = ((wr * 16 + wc) * 64 + i) * 64;
        const int rbase = i * 64;
        #pragma unroll
        for (int j = 0; j < 64; j++) {
            const uint4* krow = reinterpret_cast<const uint4*>(sm_k + (h * 64 + j) * 32);
            float s = 0.0f;
            #pragma unroll
            for (int g = 0; g < 4; g++) {
                float kv[8]; up8(krow[g], kv);
                #pragma unroll
                for (int k = 0; k < 8; k++) s += qr[g * 8 + k] * kv[k];
            }
            s += bias_table[rel_index[rbase + j] * 4 + h];
            s += attn_mask[mbase + j];
            p[j] = s;
            mx = fmaxf(mx, s);
        }
        float sum = 0.0f;
        #pragma unroll
        for (int j = 0; j < 64; j++) { p[j] = __expf(p[j] - mx); sum += p[j]; }
        const float inv = 1.0f / sum;
        float acc[32];
        #pragma unroll
        for (int d = 0; d < 32; d++) acc[d] = 0.0f;
        #pragma unroll
        for (int j = 0; j < 64; j++) {
            const float pj = p[j];
            const uint4* vrow = reinterpret_cast<const uint4*>(sm_v + (h * 64 + j) * 32);
            #pragma unroll
            for (int g = 0; g < 4; g++) {
                float vv[8]; up8(vrow[g], vv);
                #pragma unroll
                for (int k = 0; k < 8; k++) acc[g * 8 + k] += pj * vv[k];
            }
        }
        // attention out (token i, channels h*32..h*32+31) -> sm_xw (bf16), reuse
        u16* arow = sm_xw + i * 128 + h * 32;
        #pragma unroll
        for (int g = 0; g < 4; g++) {
            uint4 st;
            st.x = pk2(acc[g * 8 + 0] * inv, acc[g * 8 + 1] * inv);
            st.y = pk2(acc[g * 8 + 2] * inv, acc[g * 8 + 3] * inv);
            st.z = pk2(acc[g * 8 + 4] * inv, acc[g * 8 + 5] * inv);
            st.w = pk2(acc[g * 8 + 6] * inv, acc[g * 8 + 7] * inv);
            *reinterpret_cast<uint4*>(arow + g * 8) = st;
        }
    }
    __syncthreads();

    // ---- Phase 4: proj: out2 = ao @ w_proj + b_proj -> sm_o2 (fp32) ----
    for (int rep = 0; rep < 4; rep++) {
        const int ol = (rep * 256 + tid) * 8;
        const int t = ol >> 7, c = ol & 127;
        float acc[8];
        {
            const float4 b0 = *reinterpret_cast<const float4*>(b_proj + c);
            const float4 b1 = *reinterpret_cast<const float4*>(b_proj + c + 4);
            acc[0] = b0.x; acc[1] = b0.y; acc[2] = b0.z; acc[3] = b0.w;
            acc[4] = b1.x; acc[5] = b1.y; acc[6] = b1.z; acc[7] = b1.w;
        }
        const u16* ar = sm_xw + t * 128;
        const float* wp = w_proj + c;
        #pragma unroll 2
        for (int c2 = 0; c2 < 128; c2++) {
            const float av = b2f(ar[c2]);
            const float4 w0 = *reinterpret_cast<const float4*>(wp + c2 * 128);
            const float4 w1 = *reinterpret_cast<const float4*>(wp + c2 * 128 + 4);
            acc[0] += av * w0.x; acc[1] += av * w0.y; acc[2] += av * w0.z; acc[3] += av * w0.w;
            acc[4] += av * w1.x; acc[5] += av * w1.y; acc[6] += av * w1.z; acc[7] += av * w1.w;
        }
        float4* dst = reinterpret_cast<float4*>(sm_o2 + ol);
        dst[0] = make_float4(acc[0], acc[1], acc[2], acc[3]);
        dst[1] = make_float4(acc[4], acc[5], acc[6], acc[7]);
    }
    __syncthreads();

    // ---- Phase 5: LN1 + residual, write x1 (fp32) at unshifted location ----
    if (tid < 64) {
        const int t = tid;
        const float* r = sm_o2 + t * 128;
        float sm = 0.0f, sq = 0.0f;
        #pragma unroll 4
        for (int c = 0; c < 128; c++) { const float v = r[c]; sm += v; sq += v * v; }
        const float m = sm * 0.0078125f;
        const float var = fmaxf(sq * 0.0078125f - m * m, 0.0f);
        const float rs = rsqrtf(var + EPS_);
        const int i = t >> 3, j = t & 7;
        const int hh = (wr * 8 + i + 4) & 127;
        const int ww = (wc * 8 + j + 4) & 127;
        const size_t gbase = ((size_t)((b * 128 + hh) * 128 + ww)) * 128;
        for (int c8 = 0; c8 < 128; c8 += 8) {
            const float4 x0 = *reinterpret_cast<const float4*>(x + gbase + c8);
            const float4 x1v = *reinterpret_cast<const float4*>(x + gbase + c8 + 4);
            const float4 g0 = *reinterpret_cast<const float4*>(g1 + c8);
            const float4 g1v = *reinterpret_cast<const float4*>(g1 + c8 + 4);
            const float4 e0 = *reinterpret_cast<const float4*>(be1 + c8);
            const float4 e1 = *reinterpret_cast<const float4*>(be1 + c8 + 4);
            float xv[8] = {x0.x, x0.y, x0.z, x0.w, x1v.x, x1v.y, x1v.z, x1v.w};
            float gv[8] = {g0.x, g0.y, g0.z, g0.w, g1v.x, g1v.y, g1v.z, g1v.w};
            float bv[8] = {e0.x, e0.y, e0.z, e0.w, e1.x, e1.y, e1.z, e1.w};
            float o[8];
            #pragma unroll
            for (int k = 0; k < 8; k++)
                o[k] = xv[k] + (r[c8 + k] - m) * rs * gv[k] + bv[k];
            *reinterpret_cast<float4*>(x1out + gbase + c8)     = make_float4(o[0], o[1], o[2], o[3]);
            *reinterpret_cast<float4*>(x1out + gbase + c8 + 4) = make_float4(o[4], o[5], o[6], o[7]);
        }
    }
}

// =====================================================================
// Kernel B: MLP (fc1 -> exact GELU -> fc2) + LN2 + residual, IN-PLACE on x1
// one block per 64 tokens; tile staged to LDS before write-back.
// =====================================================================
__global__ __launch_bounds__(256) void swin_mlp(
    float* __restrict__ x1io, const float* __restrict__ w_fc1, const float* __restrict__ b_fc1,
    const float* __restrict__ w_fc2, const float* __restrict__ b_fc2,
    const float* __restrict__ g2, const float* __restrict__ be2)
{
    __shared__ __align__(16) float sm_xt[8192];   // 32 KB fp32: x1 tile (also residual)
    __shared__ __align__(16) float sm_h[8192];    // 32 KB fp32: hidden chunk / final h2
    const int tid = threadIdx.x;
    const size_t base = (size_t)blockIdx.x * 8192;   // 64 tokens * 128 ch

    for (int e = tid * 4; e < 8192; e += 1024)
        *reinterpret_cast<float4*>(sm_xt + e) = *reinterpret_cast<const float4*>(x1io + base + e);
    __syncthreads();

    float facc[32];
    #pragma unroll
    for (int rep = 0; rep < 4; rep++) {
        const int c = ((rep * 256 + tid) * 8) & 127;
        const float4 b0 = *reinterpret_cast<const float4*>(b_fc2 + c);
        const float4 b1 = *reinterpret_cast<const float4*>(b_fc2 + c + 4);
        facc[rep * 8 + 0] = b0.x; facc[rep * 8 + 1] = b0.y; facc[rep * 8 + 2] = b0.z; facc[rep * 8 + 3] = b0.w;
        facc[rep * 8 + 4] = b1.x; facc[rep * 8 + 5] = b1.y; facc[rep * 8 + 6] = b1.z; facc[rep * 8 + 7] = b1.w;
    }

    for (int chunk = 0; chunk < 4; chunk++) {
        const int u0 = chunk * 128;
        if (chunk) __syncthreads();   // previous accumulate done reading sm_h
        // fc1 + exact gelu -> sm_h (fp32)
        for (int rep = 0; rep < 4; rep++) {
            const int ol = (rep * 256 + tid) * 8;
            const int t = ol >> 7, u = ol & 127;
            float acc[8];
            {
                const float4 b0 = *reinterpret_cast<const float4*>(b_fc1 + u0 + u);
                const float4 b1 = *reinterpret_cast<const float4*>(b_fc1 + u0 + u + 4);
                acc[0] = b0.x; acc[1] = b0.y; acc[2] = b0.z; acc[3] = b0.w;
                acc[4] = b1.x; acc[5] = b1.y; acc[6] = b1.z; acc[7] = b1.w;
            }
            const float* xr = sm_xt + t * 128;
            const float* wp = w_fc1 + u0 + u;
            #pragma unroll 2
            for (int c = 0; c < 128; c++) {
                const float xv = xr[c];
                const float4 w0 = *reinterpret_cast<const float4*>(wp + c * 512);
                const float4 w1 = *reinterpret_cast<const float4*>(wp + c * 512 + 4);
                acc[0] += xv * w0.x; acc[1] += xv * w0.y; acc[2] += xv * w0.z; acc[3] += xv * w0.w;
                acc[4] += xv * w1.x; acc[5] += xv * w1.y; acc[6] += xv * w1.z; acc[7] += xv * w1.w;
            }
            #pragma unroll
            for (int k = 0; k < 8; k++)
                acc[k] = 0.5f * acc[k] * (1.0f + erff(acc[k] * 0.70710678118654752f));
            float4* dst = reinterpret_cast<float4*>(sm_h + ol);
            dst[0] = make_float4(acc[0], acc[1], acc[2], acc[3]);
            dst[1] = make_float4(acc[4], acc[5], acc[6], acc[7]);
        }
        __syncthreads();
        // fc2 accumulate (registers)
        for (int rep = 0; rep < 4; rep++) {
            const int ol = (rep * 256 + tid) * 8;
            const int t = ol >> 7, c = ol & 127;
            const float* hr = sm_h + t * 128;
            const float* wp = w_fc2 + (size_t)u0 * 128 + c;
            float a[8];
            #pragma unroll
            for (int k = 0; k < 8; k++) a[k] = facc[rep * 8 + k];
            #pragma unroll 2
            for (int u = 0; u < 128; u++) {
                const float hv = hr[u];
                const float4 w0 = *reinterpret_cast<const float4*>(wp + u * 128);
                const float4 w1 = *reinterpret_cast<const float4*>(wp + u * 128 + 4);
                a[0] += hv * w0.x; a[1] += hv * w0.y; a[2] += hv * w0.z; a[3] += hv * w0.w;
                a[4] += hv * w1.x; a[5] += hv * w1.y; a[6] += hv * w1.z; a[7] += hv * w1.w;
            }
            #pragma unroll
            for (int k = 0; k < 8; k++) facc[rep * 8 + k] = a[k];
        }
    }
    __syncthreads();
    // h2 -> sm_h (fp32)
    for (int rep = 0; rep < 4; rep++) {
        const int ol = (rep * 256 + tid) * 8;
        float4* dst = reinterpret_cast<float4*>(sm_h + ol);
        dst[0] = make_float4(facc[rep * 8 + 0], facc[rep * 8 + 1], facc[rep * 8 + 2], facc[rep * 8 + 3]);
        dst[1] = make_float4(facc[rep * 8 + 4], facc[rep * 8 + 5], facc[rep * 8 + 6], facc[rep * 8 + 7]);
    }
    __syncthreads();
    // LN2 + residual -> write back in place
    if (tid < 64) {
        const int t = tid;
        const float* r = sm_h + t * 128;
        float sm = 0.0f, sq = 0.0f;
        #pragma unroll 4
        for (int c = 0; c < 128; c++) { const float v = r[c]; sm += v; sq += v * v; }
        const float m = sm * 0.0078125f;
        const float var = fmaxf(sq * 0.0078125f - m * m, 0.0f);
        const float rs = rsqrtf(var + EPS_);
        for (int c8 = 0; c8 < 128; c8 += 8) {
            const float4 g0 = *reinterpret_cast<const float4*>(g2 + c8);
            const float4 g1v = *reinterpret_cast<const float4*>(g2 + c8 + 4);
            const float4 e0 = *reinterpret_cast<const float4*>(be2 + c8);
            const float4 e1 = *reinterpret_cast<const float4*>(be2 + c8 + 4);
            float gv[8] = {g0.x, g0.y, g0.z, g0.w, g1v.x, g1v.y, g1v.z, g1v.w};
            float bv[8] = {e0.x, e0.y, e0.z, e0.w, e1.x, e1.y, e1.z, e1.w};
            const float* xr = sm_xt + t * 128 + c8;
            float o[8];
            #pragma unroll
            for (int k = 0; k < 8; k++)
                o[k] = xr[k] + (r[c8 + k] - m) * rs * gv[k] + bv[k];
            *reinterpret_cast<float4*>(x1io + base + t * 128 + c8)     = make_float4(o[0], o[1], o[2], o[3]);
            *reinterpret_cast<float4*>(x1io + base + t * 128 + c8 + 4) = make_float4(o[4], o[5], o[6], o[7]);
        }
    }
}

extern "C" void kernel_launch(void* const* d_in, const int* in_sizes, int n_in,
                              void* d_out, int out_size, void* d_ws, size_t ws_size,
                              hipStream_t stream) {
    const float* x         = (const float*)d_in[0];
    const float* w_qkv     = (const float*)d_in[1];
    const float* b_qkv     = (const float*)d_in[2];
    const float* bias_tab  = (const float*)d_in[3];
    const float* w_proj    = (const float*)d_in[4];
    const float* b_proj    = (const float*)d_in[5];
    const float* g1        = (const float*)d_in[6];
    const float* be1       = (const float*)d_in[7];
    const float* w_fc1     = (const float*)d_in[8];
    const float* b_fc1     = (const float*)d_in[9];
    const float* w_fc2     = (const float*)d_in[10];
    const float* b_fc2     = (const float*)d_in[11];
    const float* g2        = (const float*)d_in[12];
    const float* be2       = (const float*)d_in[13];
    const int* rel_index   = (const int*)d_in[14];
    const float* attn_mask = (const float*)d_in[15];

    // x1 lives in d_out (exactly out_size fp32 elements); kernel B is
    // per-tile in-place, so no workspace is needed at all.
    float* x1 = (float*)d_out;

    swin_attn<<<4096, 256, 0, stream>>>(x, w_qkv, b_qkv, bias_tab, w_proj, b_proj,
                                        g1, be1, rel_index, attn_mask, x1);
    swin_mlp<<<4096, 256, 0, stream>>>(x1, w_fc1, b_fc1, w_fc2, b_fc2, g2, be2);
}

// Round 3
// 702.149 us; speedup vs baseline: 10.8916x; 10.8916x over previous
//
#include <hip/hip_runtime.h>
#include <hip/hip_bf16.h>
#include <math.h>

typedef unsigned short u16;
typedef unsigned int   u32;

typedef __bf16 bf16x8 __attribute__((ext_vector_type(8)));
typedef float  f32x4  __attribute__((ext_vector_type(4)));
#define MFMA_B16 __builtin_amdgcn_mfma_f32_16x16x32_bf16

__device__ __forceinline__ u16 f2b(float f) {
    union { float f; u32 i; } v; v.f = f;
    u32 x = v.i;
    u32 r = x + 0x7fffu + ((x >> 16) & 1u);   // RNE
    return (u16)(r >> 16);
}
__device__ __forceinline__ u32 pk2(float a, float b) {
    return (u32)f2b(a) | ((u32)f2b(b) << 16);
}
__device__ __forceinline__ bf16x8 pk8(float4 f0, float4 f1) {
    union { u32 u[4]; bf16x8 v; } cv;
    cv.u[0] = pk2(f0.x, f0.y); cv.u[1] = pk2(f0.z, f0.w);
    cv.u[2] = pk2(f1.x, f1.y); cv.u[3] = pk2(f1.z, f1.w);
    return cv.v;
}

#define SCALE_ 0.17677669529663687f   // 32^-0.5
#define EPS_   1e-3f

// ---------------- workspace layout (bytes) ----------------
// 0       : wqkvT  bf16 [384][128]   (98304 B)
// 98304   : wprojT bf16 [128][128]   (32768 B)
// 131072  : w1T    bf16 [512][128]   (131072 B)
// 262144  : w2T    bf16 [128][512]   (131072 B)
// 393216  : rpbm   fp32 [4][4][64][64] (262144 B)   rpb + shift-mask folded
// total 655360 B

// =====================================================================
// Prep: transpose weights -> bf16 B^T layouts; fold rpb + mask (4 classes)
// =====================================================================
__global__ __launch_bounds__(256) void swin_prep(
    const float* __restrict__ w_qkv, const float* __restrict__ w_proj,
    const float* __restrict__ w_fc1, const float* __restrict__ w_fc2,
    const float* __restrict__ bias_table, const int* __restrict__ rel_index,
    const float* __restrict__ attn_mask,
    u16* __restrict__ wqkvT, u16* __restrict__ wprojT,
    u16* __restrict__ w1T, u16* __restrict__ w2T, float* __restrict__ rpbm)
{
    const int idx = blockIdx.x * 256 + threadIdx.x;
    if (idx < 49152) {                       // qkv: [o<384][c<128]
        const int o = idx >> 7, c = idx & 127;
        wqkvT[idx] = f2b(w_qkv[c * 384 + o]);
    } else if (idx < 65536) {                // proj: [o<128][c<128]
        const int i2 = idx - 49152;
        const int o = i2 >> 7, c = i2 & 127;
        wprojT[i2] = f2b(w_proj[c * 128 + o]);
    } else if (idx < 131072) {               // fc1: [o<512][c<128]
        const int i2 = idx - 65536;
        const int o = i2 >> 7, c = i2 & 127;
        w1T[i2] = f2b(w_fc1[c * 512 + o]);
    } else if (idx < 196608) {               // fc2: [o<128][u<512]
        const int i2 = idx - 131072;
        const int o = i2 >> 9, u = i2 & 511;
        w2T[i2] = f2b(w_fc2[u * 128 + o]);
    } else if (idx < 262144) {               // rpbm[cls][h][i][j]
        const int i2 = idx - 196608;
        const int cls = i2 >> 14, rem = i2 & 16383;
        const int h = rem >> 12, ij = rem & 4095;
        const int widx = ((cls & 2) ? 240 : 0) + ((cls & 1) ? 15 : 0);
        rpbm[i2] = bias_table[rel_index[ij] * 4 + h] + attn_mask[widx * 4096 + ij];
    }
}

// =====================================================================
// Kernel A: shifted-window attention (MFMA) + proj + LN1 + residual -> x1
// one block per window; wave w == head w.
// LDS (u16 elems): q[4][64][40] @0, k @10240, vT[4][32][72] @20480,
//   P[4][64][72] @0 (post-barrier), attn_out[64][136] @0 (post-PV-barrier),
//   X2 fp32 [64][132] @ float-idx 4352.  Total 29696 elems = 59392 B.
// =====================================================================
#define QA_OFF 0
#define KA_OFF 10240
#define VA_OFF 20480
#define PA_OFF 0
#define AO_OFF 0
#define X2F_OFF 4352

__global__ __launch_bounds__(256) void swin_attn_mfma(
    const float* __restrict__ x, const u16* __restrict__ wqkvT, const float* __restrict__ b_qkv,
    const u16* __restrict__ wprojT, const float* __restrict__ b_proj,
    const float* __restrict__ g1, const float* __restrict__ be1,
    const float* __restrict__ rpbm, float* __restrict__ x1out)
{
    __shared__ __align__(16) u16 sm[29696];
    const int tid  = threadIdx.x;
    const int w    = tid >> 6;          // wave / head
    const int lane = tid & 63;
    const int l15  = lane & 15;
    const int quad = lane >> 4;
    const int win  = blockIdx.x;
    const int b = win >> 8, wr = (win >> 4) & 15, wc = win & 15;

    // token-row global bases for A-fragment rows t = mi*16 + l15
    size_t rowb[4];
    #pragma unroll
    for (int mi = 0; mi < 4; mi++) {
        const int t  = mi * 16 + l15;
        const int hh = (wr * 8 + (t >> 3) + 4) & 127;
        const int ww = (wc * 8 + (t & 7) + 4) & 127;
        rowb[mi] = ((size_t)((b * 128 + hh) * 128 + ww)) * 128;
    }

    // ---- Phase 1: QKV GEMM (A from global fp32, B = wqkvT bf16 L2-hot) ----
    {
        f32x4 acc[6][4];
        #pragma unroll
        for (int n = 0; n < 6; n++) {
            const float bq = b_qkv[w * 96 + n * 16 + l15];
            #pragma unroll
            for (int mi = 0; mi < 4; mi++) acc[n][mi] = (f32x4){bq, bq, bq, bq};
        }
        #pragma unroll
        for (int ks = 0; ks < 4; ks++) {
            bf16x8 a[4], bb[6];
            #pragma unroll
            for (int mi = 0; mi < 4; mi++) {
                const float4 f0 = *(const float4*)(x + rowb[mi] + ks * 32 + quad * 8);
                const float4 f1 = *(const float4*)(x + rowb[mi] + ks * 32 + quad * 8 + 4);
                a[mi] = pk8(f0, f1);
            }
            #pragma unroll
            for (int n = 0; n < 6; n++)
                bb[n] = *(const bf16x8*)(wqkvT + (size_t)(w * 96 + n * 16 + l15) * 128 + ks * 32 + quad * 8);
            #pragma unroll
            for (int n = 0; n < 6; n++)
                #pragma unroll
                for (int mi = 0; mi < 4; mi++)
                    acc[n][mi] = MFMA_B16(a[mi], bb[n], acc[n][mi], 0, 0, 0);
        }
        // scatter to q/k (row-major, stride 40) and vT ([d][t], stride 72)
        #pragma unroll
        for (int n = 0; n < 6; n++) {
            const int o = w * 96 + n * 16 + l15;
            const int s = o >> 7, h = (o >> 5) & 3, d = o & 31;
            #pragma unroll
            for (int mi = 0; mi < 4; mi++) {
                if (s < 2) {
                    const int base = (s ? KA_OFF : QA_OFF) + h * 2560 + d;
                    const float sc = s ? 1.0f : SCALE_;
                    #pragma unroll
                    for (int r = 0; r < 4; r++)
                        sm[base + (mi * 16 + quad * 4 + r) * 40] = f2b(acc[n][mi][r] * sc);
                } else {
                    const int t0 = mi * 16 + quad * 4;
                    const u32 w0 = pk2(acc[n][mi][0], acc[n][mi][1]);
                    const u32 w1 = pk2(acc[n][mi][2], acc[n][mi][3]);
                    *(uint2*)(sm + VA_OFF + h * 2304 + d * 72 + t0) = make_uint2(w0, w1);
                }
            }
        }
    }
    __syncthreads();

    // ---- Phase 2: scores (MFMA, K=32 single step) + softmax (registers) ----
    float sinv[4][4];
    {
        const int h = w;
        const float* rb = rpbm + (size_t)((((wr == 15) ? 2 : 0) | ((wc == 15) ? 1 : 0)) * 4 + h) * 4096;
        f32x4 S[4][4];
        #pragma unroll
        for (int mi = 0; mi < 4; mi++)
            #pragma unroll
            for (int ni = 0; ni < 4; ni++)
                #pragma unroll
                for (int r = 0; r < 4; r++)
                    S[mi][ni][r] = rb[(mi * 16 + quad * 4 + r) * 64 + ni * 16 + l15];
        bf16x8 aq[4], bk[4];
        #pragma unroll
        for (int mi = 0; mi < 4; mi++)
            aq[mi] = *(const bf16x8*)(sm + QA_OFF + h * 2560 + (mi * 16 + l15) * 40 + quad * 8);
        #pragma unroll
        for (int ni = 0; ni < 4; ni++)
            bk[ni] = *(const bf16x8*)(sm + KA_OFF + h * 2560 + (ni * 16 + l15) * 40 + quad * 8);
        #pragma unroll
        for (int mi = 0; mi < 4; mi++)
            #pragma unroll
            for (int ni = 0; ni < 4; ni++)
                S[mi][ni] = MFMA_B16(aq[mi], bk[ni], S[mi][ni], 0, 0, 0);
        // softmax over j (16 lanes x 4 ni-tiles) per row
        #pragma unroll
        for (int mi = 0; mi < 4; mi++) {
            #pragma unroll
            for (int r = 0; r < 4; r++) {
                float m0 = fmaxf(fmaxf(S[mi][0][r], S[mi][1][r]), fmaxf(S[mi][2][r], S[mi][3][r]));
                m0 = fmaxf(m0, __shfl_xor(m0, 1));
                m0 = fmaxf(m0, __shfl_xor(m0, 2));
                m0 = fmaxf(m0, __shfl_xor(m0, 4));
                m0 = fmaxf(m0, __shfl_xor(m0, 8));
                float s0 = 0.0f;
                #pragma unroll
                for (int ni = 0; ni < 4; ni++) {
                    const float e = __expf(S[mi][ni][r] - m0);
                    S[mi][ni][r] = e;
                    s0 += e;
                }
                s0 += __shfl_xor(s0, 1);
                s0 += __shfl_xor(s0, 2);
                s0 += __shfl_xor(s0, 4);
                s0 += __shfl_xor(s0, 8);
                sinv[mi][r] = 1.0f / s0;
            }
        }
        __syncthreads();   // q/k reads done everywhere; P may overwrite them

        // ---- Phase 3: P -> LDS (raw exp), PV (MFMA), scale by 1/sum ----
        #pragma unroll
        for (int mi = 0; mi < 4; mi++)
            #pragma unroll
            for (int ni = 0; ni < 4; ni++)
                #pragma unroll
                for (int r = 0; r < 4; r++)
                    sm[PA_OFF + h * 4608 + (mi * 16 + quad * 4 + r) * 72 + ni * 16 + l15] = f2b(S[mi][ni][r]);

        f32x4 O[4][2];
        #pragma unroll
        for (int mi = 0; mi < 4; mi++)
            #pragma unroll
            for (int ni = 0; ni < 2; ni++) O[mi][ni] = (f32x4){0.f, 0.f, 0.f, 0.f};
        #pragma unroll
        for (int ks = 0; ks < 2; ks++) {
            bf16x8 ap[4], bv[2];
            #pragma unroll
            for (int mi = 0; mi < 4; mi++)
                ap[mi] = *(const bf16x8*)(sm + PA_OFF + h * 4608 + (mi * 16 + l15) * 72 + ks * 32 + quad * 8);
            #pragma unroll
            for (int ni = 0; ni < 2; ni++)
                bv[ni] = *(const bf16x8*)(sm + VA_OFF + h * 2304 + (ni * 16 + l15) * 72 + ks * 32 + quad * 8);
            #pragma unroll
            for (int mi = 0; mi < 4; mi++)
                #pragma unroll
                for (int ni = 0; ni < 2; ni++)
                    O[mi][ni] = MFMA_B16(ap[mi], bv[ni], O[mi][ni], 0, 0, 0);
        }
        __syncthreads();   // all PV reads of P/vT done; attn_out may overlay

        #pragma unroll
        for (int mi = 0; mi < 4; mi++)
            #pragma unroll
            for (int ni = 0; ni < 2; ni++)
                #pragma unroll
                for (int r = 0; r < 4; r++)
                    sm[AO_OFF + (mi * 16 + quad * 4 + r) * 136 + h * 32 + ni * 16 + l15]
                        = f2b(O[mi][ni][r] * sinv[mi][r]);
    }
    __syncthreads();

    // ---- Phase 4: proj (MFMA) -> X2 fp32 LDS ----
    {
        f32x4 X2[4][2];
        #pragma unroll
        for (int ni = 0; ni < 2; ni++) {
            const float bp = b_proj[w * 32 + ni * 16 + l15];
            #pragma unroll
            for (int mi = 0; mi < 4; mi++) X2[mi][ni] = (f32x4){bp, bp, bp, bp};
        }
        #pragma unroll
        for (int ks = 0; ks < 4; ks++) {
            bf16x8 aa[4], bw[2];
            #pragma unroll
            for (int mi = 0; mi < 4; mi++)
                aa[mi] = *(const bf16x8*)(sm + AO_OFF + (mi * 16 + l15) * 136 + ks * 32 + quad * 8);
            #pragma unroll
            for (int ni = 0; ni < 2; ni++)
                bw[ni] = *(const bf16x8*)(wprojT + (size_t)(w * 32 + ni * 16 + l15) * 128 + ks * 32 + quad * 8);
            #pragma unroll
            for (int mi = 0; mi < 4; mi++)
                #pragma unroll
                for (int ni = 0; ni < 2; ni++)
                    X2[mi][ni] = MFMA_B16(aa[mi], bw[ni], X2[mi][ni], 0, 0, 0);
        }
        float* X2f = (float*)sm + X2F_OFF;
        #pragma unroll
        for (int mi = 0; mi < 4; mi++)
            #pragma unroll
            for (int ni = 0; ni < 2; ni++)
                #pragma unroll
                for (int r = 0; r < 4; r++)
                    X2f[(mi * 16 + quad * 4 + r) * 132 + w * 32 + ni * 16 + l15] = X2[mi][ni][r];
    }
    __syncthreads();

    // ---- Phase 5: LN1 + residual (4 threads per token row) ----
    {
        const int t = tid >> 2, part = tid & 3;
        const float* Xr = (const float*)sm + X2F_OFF + t * 132 + part * 32;
        float s1 = 0.f, s2 = 0.f;
        #pragma unroll
        for (int c = 0; c < 32; c++) { const float v = Xr[c]; s1 += v; s2 += v * v; }
        s1 += __shfl_xor(s1, 1); s1 += __shfl_xor(s1, 2);
        s2 += __shfl_xor(s2, 1); s2 += __shfl_xor(s2, 2);
        const float m  = s1 * 0.0078125f;
        const float vr = fmaxf(s2 * 0.0078125f - m * m, 0.f);
        const float rs = rsqrtf(vr + EPS_);
        const int hh = (wr * 8 + (t >> 3) + 4) & 127;
        const int ww = (wc * 8 + (t & 7) + 4) & 127;
        const size_t g = ((size_t)((b * 128 + hh) * 128 + ww)) * 128 + part * 32;
        #pragma unroll
        for (int c4 = 0; c4 < 32; c4 += 4) {
            const float4 xv = *(const float4*)(x + g + c4);
            const float4 gv = *(const float4*)(g1 + part * 32 + c4);
            const float4 bv = *(const float4*)(be1 + part * 32 + c4);
            float4 o;
            o.x = xv.x + (Xr[c4 + 0] - m) * rs * gv.x + bv.x;
            o.y = xv.y + (Xr[c4 + 1] - m) * rs * gv.y + bv.y;
            o.z = xv.z + (Xr[c4 + 2] - m) * rs * gv.z + bv.z;
            o.w = xv.w + (Xr[c4 + 3] - m) * rs * gv.w + bv.w;
            *(float4*)(x1out + g + c4) = o;
        }
    }
}

// =====================================================================
// Kernel B: MLP (fc1 -> GELU -> fc2, MFMA) + LN2 + residual, in-place on x1
// LDS: xt bf16 [64][136] @0 ; h bf16 [64][264] @8704 ; X3 fp32 over h.
// Total 25600 elems = 51200 B.
// =====================================================================
#define HB_OFF 8704
#define X3F_OFF 4352

__global__ __launch_bounds__(256) void swin_mlp_mfma(
    float* __restrict__ x1io, const u16* __restrict__ w1T, const float* __restrict__ b_fc1,
    const u16* __restrict__ w2T, const float* __restrict__ b_fc2,
    const float* __restrict__ g2, const float* __restrict__ be2)
{
    __shared__ __align__(16) u16 sm[25600];
    const int tid  = threadIdx.x;
    const int w    = tid >> 6;
    const int lane = tid & 63;
    const int l15  = lane & 15;
    const int quad = lane >> 4;
    const size_t base = (size_t)blockIdx.x * 8192;

    for (int e = tid * 8; e < 8192; e += 2048) {
        const int t = e >> 7, c = e & 127;
        const float4 f0 = *(const float4*)(x1io + base + e);
        const float4 f1 = *(const float4*)(x1io + base + e + 4);
        union { bf16x8 v; uint4 u; } cv; cv.v = pk8(f0, f1);
        *(uint4*)(sm + t * 136 + c) = cv.u;
    }
    __syncthreads();

    f32x4 acc2[2][4];   // [ni][mi] fc2 accumulator, persists across chunks
    #pragma unroll
    for (int ni = 0; ni < 2; ni++) {
        const float bb = b_fc2[w * 32 + ni * 16 + l15];
        #pragma unroll
        for (int mi = 0; mi < 4; mi++) acc2[ni][mi] = (f32x4){bb, bb, bb, bb};
    }

    for (int ch = 0; ch < 2; ch++) {
        // fc1 chunk (256 hidden cols) + GELU -> h LDS
        f32x4 a1[4][4];   // [ni][mi]
        #pragma unroll
        for (int ni = 0; ni < 4; ni++) {
            const float bb = b_fc1[ch * 256 + (w * 4 + ni) * 16 + l15];
            #pragma unroll
            for (int mi = 0; mi < 4; mi++) a1[ni][mi] = (f32x4){bb, bb, bb, bb};
        }
        #pragma unroll
        for (int ks = 0; ks < 4; ks++) {
            bf16x8 af[4], bf[4];
            #pragma unroll
            for (int mi = 0; mi < 4; mi++)
                af[mi] = *(const bf16x8*)(sm + (mi * 16 + l15) * 136 + ks * 32 + quad * 8);
            #pragma unroll
            for (int ni = 0; ni < 4; ni++)
                bf[ni] = *(const bf16x8*)(w1T + (size_t)(ch * 256 + (w * 4 + ni) * 16 + l15) * 128 + ks * 32 + quad * 8);
            #pragma unroll
            for (int ni = 0; ni < 4; ni++)
                #pragma unroll
                for (int mi = 0; mi < 4; mi++)
                    a1[ni][mi] = MFMA_B16(af[mi], bf[ni], a1[ni][mi], 0, 0, 0);
        }
        #pragma unroll
        for (int ni = 0; ni < 4; ni++)
            #pragma unroll
            for (int mi = 0; mi < 4; mi++)
                #pragma unroll
                for (int r = 0; r < 4; r++) {
                    float v = a1[ni][mi][r];
                    v = 0.5f * v * (1.0f + erff(v * 0.70710678118654752f));
                    sm[HB_OFF + (mi * 16 + quad * 4 + r) * 264 + (w * 4 + ni) * 16 + l15] = f2b(v);
                }
        __syncthreads();
        // fc2 partial accumulate over this chunk
        #pragma unroll
        for (int ks = 0; ks < 8; ks++) {
            bf16x8 ah[4], bh[2];
            #pragma unroll
            for (int mi = 0; mi < 4; mi++)
                ah[mi] = *(const bf16x8*)(sm + HB_OFF + (mi * 16 + l15) * 264 + ks * 32 + quad * 8);
            #pragma unroll
            for (int ni = 0; ni < 2; ni++)
                bh[ni] = *(const bf16x8*)(w2T + (size_t)(w * 32 + ni * 16 + l15) * 512 + ch * 256 + ks * 32 + quad * 8);
            #pragma unroll
            for (int ni = 0; ni < 2; ni++)
                #pragma unroll
                for (int mi = 0; mi < 4; mi++)
                    acc2[ni][mi] = MFMA_B16(ah[mi], bh[ni], acc2[ni][mi], 0, 0, 0);
        }
        __syncthreads();   // h dead; next chunk (or X3) may overwrite
    }

    // X3 fp32 into h region
    {
        float* X3 = (float*)sm + X3F_OFF;
        #pragma unroll
        for (int ni = 0; ni < 2; ni++)
            #pragma unroll
            for (int mi = 0; mi < 4; mi++)
                #pragma unroll
                for (int r = 0; r < 4; r++)
                    X3[(mi * 16 + quad * 4 + r) * 132 + w * 32 + ni * 16 + l15] = acc2[ni][mi][r];
    }
    __syncthreads();

    // LN2 + residual (4 threads per token row), write back in place
    {
        const int t = tid >> 2, part = tid & 3;
        const float* Xr = (const float*)sm + X3F_OFF + t * 132 + part * 32;
        float s1 = 0.f, s2 = 0.f;
        #pragma unroll
        for (int c = 0; c < 32; c++) { const float v = Xr[c]; s1 += v; s2 += v * v; }
        s1 += __shfl_xor(s1, 1); s1 += __shfl_xor(s1, 2);
        s2 += __shfl_xor(s2, 1); s2 += __shfl_xor(s2, 2);
        const float m  = s1 * 0.0078125f;
        const float vr = fmaxf(s2 * 0.0078125f - m * m, 0.f);
        const float rs = rsqrtf(vr + EPS_);
        const size_t g = base + t * 128 + part * 32;
        #pragma unroll
        for (int c4 = 0; c4 < 32; c4 += 4) {
            const float4 xv = *(const float4*)(x1io + g + c4);
            const float4 gv = *(const float4*)(g2 + part * 32 + c4);
            const float4 bv = *(const float4*)(be2 + part * 32 + c4);
            float4 o;
            o.x = xv.x + (Xr[c4 + 0] - m) * rs * gv.x + bv.x;
            o.y = xv.y + (Xr[c4 + 1] - m) * rs * gv.y + bv.y;
            o.z = xv.z + (Xr[c4 + 2] - m) * rs * gv.z + bv.z;
            o.w = xv.w + (Xr[c4 + 3] - m) * rs * gv.w + bv.w;
            *(float4*)(x1io + g + c4) = o;
        }
    }
}

extern "C" void kernel_launch(void* const* d_in, const int* in_sizes, int n_in,
                              void* d_out, int out_size, void* d_ws, size_t ws_size,
                              hipStream_t stream) {
    const float* x         = (const float*)d_in[0];
    const float* w_qkv     = (const float*)d_in[1];
    const float* b_qkv     = (const float*)d_in[2];
    const float* bias_tab  = (const float*)d_in[3];
    const float* w_proj    = (const float*)d_in[4];
    const float* b_proj    = (const float*)d_in[5];
    const float* g1        = (const float*)d_in[6];
    const float* be1       = (const float*)d_in[7];
    const float* w_fc1     = (const float*)d_in[8];
    const float* b_fc1     = (const float*)d_in[9];
    const float* w_fc2     = (const float*)d_in[10];
    const float* b_fc2     = (const float*)d_in[11];
    const float* g2        = (const float*)d_in[12];
    const float* be2       = (const float*)d_in[13];
    const int* rel_index   = (const int*)d_in[14];
    const float* attn_mask = (const float*)d_in[15];

    char* ws = (char*)d_ws;
    u16*   wqkvT  = (u16*)ws;
    u16*   wprojT = (u16*)(ws + 98304);
    u16*   w1T    = (u16*)(ws + 131072);
    u16*   w2T    = (u16*)(ws + 262144);
    float* rpbm   = (float*)(ws + 393216);

    float* x1 = (float*)d_out;   // x1 lives in d_out; kernel B is in-place

    swin_prep<<<1024, 256, 0, stream>>>(w_qkv, w_proj, w_fc1, w_fc2,
                                        bias_tab, rel_index, attn_mask,
                                        wqkvT, wprojT, w1T, w2T, rpbm);
    swin_attn_mfma<<<4096, 256, 0, stream>>>(x, wqkvT, b_qkv, wprojT, b_proj,
                                             g1, be1, rpbm, x1);
    swin_mlp_mfma<<<4096, 256, 0, stream>>>(x1, w1T, b_fc1, w2T, b_fc2, g2, be2);
}